// Round 1
// baseline (5181.815 us; speedup 1.0000x reference)
//
#include <hip/hip_runtime.h>
#include <hip/hip_fp16.h>
#include <stdint.h>

// LSTM policy rollout: 256 sequential steps, each = 3x (4096x4097) gemv (f16
// weights, fdot2 f32-accum) + 1x (1x4097) gemv in f32 (o gate -> sample).
// Persistent kernel, custom grid barrier (counter memset each launch).

#define HID    4096
#define CTX    1024
#define NSTEPS 256
#define NBLK   256
#define TPB    1024
#define WAVES  (TPB/64)        // 16
#define HROWS  (HID/NBLK)      // 16 h-rows per block
#define GROWS  (3*HROWS)       // 48 gate rows per block
#define RPW    (GROWS/WAVES)   // 3 gate rows per wave
#define WPAD   4104            // padded row length (f16), 8208 B = 16B-aligned
#define WOFF   65536           // byte offset of W16 inside ws

typedef _Float16 h2 __attribute__((ext_vector_type(2)));

__device__ __forceinline__ float fdot2f(uint32_t a, uint32_t b, float c) {
#if __has_builtin(__builtin_amdgcn_fdot2)
  return __builtin_amdgcn_fdot2(__builtin_bit_cast(h2, a),
                                __builtin_bit_cast(h2, b), c, false);
#else
  h2 x = __builtin_bit_cast(h2, a), y = __builtin_bit_cast(h2, b);
  return c + (float)x[0]*(float)y[0] + (float)x[1]*(float)y[1];
#endif
}

__global__ void prep(const float* __restrict__ Wf, const float* __restrict__ Wi,
                     const float* __restrict__ Wc, __half* __restrict__ W16) {
  int rid = blockIdx.x;               // 0 .. NBLK*GROWS-1
  int b = rid / GROWS, fl = rid % GROWS;
  int g = fl / HROWS, j = fl % HROWS;
  const float* src = (g==0 ? Wf : (g==1 ? Wi : Wc)) + (size_t)(b*HROWS + j)*4097;
  __half* dst = W16 + (size_t)rid * WPAD;
  for (int c = threadIdx.x; c < WPAD; c += blockDim.x)
    dst[c] = __float2half(c < 4097 ? src[c] : 0.f);
}

template<bool F16>
__global__ __launch_bounds__(TPB, 4)
void lstm(const float* __restrict__ ctx, const float* __restrict__ u,
          const float* __restrict__ l1w, const float* __restrict__ l1b,
          const float* __restrict__ Wf,  const float* __restrict__ Wfb,
          const float* __restrict__ Wi,  const float* __restrict__ Wib,
          const float* __restrict__ Wc,  const float* __restrict__ Wcb,
          const float* __restrict__ Wow, const float* __restrict__ Wob,
          const __half* __restrict__ W16,
          float* __restrict__ zb0, float* __restrict__ zb1,
          unsigned* __restrict__ cnt, float* __restrict__ out)
{
  __shared__ float    zshf[HID];        // z (h part) f32 for o-gate
  __shared__ uint32_t zsh2[HID/2];      // z packed f16x2 for gate dots
  __shared__ float    red[WAVES];
  __shared__ float    pre[GROWS];
  __shared__ float    cst[HROWS];
  __shared__ float    bias[GROWS];
  __shared__ float    x0sh;

  const int tid  = threadIdx.x;
  const int b    = blockIdx.x;
  const int wv   = tid >> 6;
  const int lane = tid & 63;

  for (int i = tid; i < HID;   i += TPB) zshf[i] = 0.f;
  for (int i = tid; i < HID/2; i += TPB) zsh2[i] = 0u;
  if (tid < HROWS) cst[tid] = 0.f;
  if (tid < GROWS) {
    int g = tid / HROWS, j = tid % HROWS;
    bias[tid] = (g==0 ? Wfb : (g==1 ? Wib : Wcb))[b*HROWS + j];
  }
  // x0 = l1_w . context + l1_b  (computed redundantly & identically per block)
  {
    float p = l1w[tid] * ctx[tid];      // CTX == TPB
    #pragma unroll
    for (int off = 32; off; off >>= 1) p += __shfl_down(p, off, 64);
    if (lane == 0) red[wv] = p;
    __syncthreads();
    if (tid == 0) {
      float ssum = 0.f;
      for (int w = 0; w < WAVES; ++w) ssum += red[w];
      x0sh = ssum + l1b[0];
    }
    __syncthreads();
  }
  float xcur = x0sh;
  float logp = 0.f;

  const __half* wrow16 = W16 + (size_t)(b*GROWS + wv*RPW) * WPAD;
  const float* rowf[RPW];
  if (!F16) {
    #pragma unroll
    for (int r = 0; r < RPW; ++r) {
      int fl = wv*RPW + r;
      int g = fl / HROWS, j = fl % HROWS;
      rowf[r] = (g==0 ? Wf : (g==1 ? Wi : Wc)) + (size_t)(b*HROWS + j)*4097;
    }
  }

  for (int t = 0; t < NSTEPS; ++t) {
    // ---- o gate (full f32, identical on every block -> consistent sample) ----
    float p = 0.f;
    #pragma unroll
    for (int k = 0; k < HID/TPB; ++k) {
      int c = tid + k*TPB;
      p = fmaf(Wow[c], zshf[c], p);
    }
    #pragma unroll
    for (int off = 32; off; off >>= 1) p += __shfl_down(p, off, 64);
    __syncthreads();
    if (lane == 0) red[wv] = p;
    __syncthreads();
    float osum = 0.f;
    #pragma unroll
    for (int w = 0; w < WAVES; ++w) osum += red[w];
    float opre = osum + Wow[HID]*xcur + Wob[0];
    float o = 1.f / (1.f + expf(-opre));
    float s = (u[t] < o) ? 1.f : 0.f;

    // ---- f/i/c gate dots: 3 rows per wave, 8 column passes of 512 ----
    float a0 = 0.f, a1 = 0.f, a2 = 0.f;
    if (F16) {
      #pragma unroll
      for (int pp = 0; pp < 8; ++pp) {
        int cb = pp*512 + lane*8;
        uint4 zz = *(const uint4*)&zsh2[cb >> 1];
        uint4 w0 = *(const uint4*)(wrow16 + cb);
        uint4 w1 = *(const uint4*)(wrow16 + WPAD   + cb);
        uint4 w2 = *(const uint4*)(wrow16 + 2*WPAD + cb);
        a0 = fdot2f(w0.x, zz.x, a0); a0 = fdot2f(w0.y, zz.y, a0);
        a0 = fdot2f(w0.z, zz.z, a0); a0 = fdot2f(w0.w, zz.w, a0);
        a1 = fdot2f(w1.x, zz.x, a1); a1 = fdot2f(w1.y, zz.y, a1);
        a1 = fdot2f(w1.z, zz.z, a1); a1 = fdot2f(w1.w, zz.w, a1);
        a2 = fdot2f(w2.x, zz.x, a2); a2 = fdot2f(w2.y, zz.y, a2);
        a2 = fdot2f(w2.z, zz.z, a2); a2 = fdot2f(w2.w, zz.w, a2);
      }
    } else {
      #pragma unroll 2
      for (int pp = 0; pp < 8; ++pp) {
        int cb = pp*512 + lane*8;
        float4 zA = *(const float4*)&zshf[cb];
        float4 zB = *(const float4*)&zshf[cb+4];
        a0 = fmaf(rowf[0][cb+0], zA.x, a0); a0 = fmaf(rowf[0][cb+1], zA.y, a0);
        a0 = fmaf(rowf[0][cb+2], zA.z, a0); a0 = fmaf(rowf[0][cb+3], zA.w, a0);
        a0 = fmaf(rowf[0][cb+4], zB.x, a0); a0 = fmaf(rowf[0][cb+5], zB.y, a0);
        a0 = fmaf(rowf[0][cb+6], zB.z, a0); a0 = fmaf(rowf[0][cb+7], zB.w, a0);
        a1 = fmaf(rowf[1][cb+0], zA.x, a1); a1 = fmaf(rowf[1][cb+1], zA.y, a1);
        a1 = fmaf(rowf[1][cb+2], zA.z, a1); a1 = fmaf(rowf[1][cb+3], zA.w, a1);
        a1 = fmaf(rowf[1][cb+4], zB.x, a1); a1 = fmaf(rowf[1][cb+5], zB.y, a1);
        a1 = fmaf(rowf[1][cb+6], zB.z, a1); a1 = fmaf(rowf[1][cb+7], zB.w, a1);
        a2 = fmaf(rowf[2][cb+0], zA.x, a2); a2 = fmaf(rowf[2][cb+1], zA.y, a2);
        a2 = fmaf(rowf[2][cb+2], zA.z, a2); a2 = fmaf(rowf[2][cb+3], zA.w, a2);
        a2 = fmaf(rowf[2][cb+4], zB.x, a2); a2 = fmaf(rowf[2][cb+5], zB.y, a2);
        a2 = fmaf(rowf[2][cb+6], zB.z, a2); a2 = fmaf(rowf[2][cb+7], zB.w, a2);
      }
    }
    #pragma unroll
    for (int off = 32; off; off >>= 1) {
      a0 += __shfl_down(a0, off, 64);
      a1 += __shfl_down(a1, off, 64);
      a2 += __shfl_down(a2, off, 64);
    }
    if (lane == 0) {
      int fl = wv*RPW;
      float xl0, xl1, xl2;
      if (F16) {
        xl0 = (float)wrow16[HID]; xl1 = (float)wrow16[WPAD+HID]; xl2 = (float)wrow16[2*WPAD+HID];
      } else {
        xl0 = rowf[0][HID]; xl1 = rowf[1][HID]; xl2 = rowf[2][HID];
      }
      pre[fl+0] = a0 + xl0*xcur + bias[fl+0];
      pre[fl+1] = a1 + xl1*xcur + bias[fl+1];
      pre[fl+2] = a2 + xl2*xcur + bias[fl+2];
    }
    __syncthreads();

    float* wb = (t & 1) ? zb0 : zb1;    // h(t) goes here; read back below
    if (tid < HROWS) {
      float ff = 1.f / (1.f + expf(-pre[tid]));
      float ii = 1.f / (1.f + expf(-pre[HROWS+tid]));
      float cc = tanhf(pre[2*HROWS+tid]);
      float cn = ff*cst[tid] + ii*cc;
      cst[tid] = cn;
      wb[b*HROWS + tid] = o * tanhf(cn);
    }
    if (b == 0 && tid == 0) {
      logp += (s != 0.f) ? logf(o) : logf(1.f - o);
      out[t] = s;
    }
    xcur = s;

    // ---- grid barrier (device-scope release/acquire) ----
    __syncthreads();
    if (tid == 0) {
      __threadfence();
      __hip_atomic_fetch_add(cnt, 1u, __ATOMIC_ACQ_REL, __HIP_MEMORY_SCOPE_AGENT);
      unsigned target = (unsigned)(t+1) * NBLK;
      while (__hip_atomic_load(cnt, __ATOMIC_ACQUIRE, __HIP_MEMORY_SCOPE_AGENT) < target)
        __builtin_amdgcn_s_sleep(4);
    }
    __syncthreads();

    // ---- reload z for next step ----
    if (t + 1 < NSTEPS) {
      const float* rb = wb;
      for (int i = tid; i < HID; i += TPB) zshf[i] = rb[i];
      for (int i = tid; i < HID/2; i += TPB) {
        h2 hv; hv[0] = (_Float16)rb[2*i]; hv[1] = (_Float16)rb[2*i+1];
        zsh2[i] = __builtin_bit_cast(uint32_t, hv);
      }
      __syncthreads();
    }
  }
  if (b == 0 && tid == 0) out[NSTEPS] = logp;
}

extern "C" void kernel_launch(void* const* d_in, const int* in_sizes, int n_in,
                              void* d_out, int out_size, void* d_ws, size_t ws_size,
                              hipStream_t stream) {
  const float* ctx = (const float*)d_in[0];
  const float* u   = (const float*)d_in[1];
  const float* l1w = (const float*)d_in[2];
  const float* l1b = (const float*)d_in[3];
  const float* Wf  = (const float*)d_in[4];
  const float* Wfb = (const float*)d_in[5];
  const float* Wi  = (const float*)d_in[6];
  const float* Wib = (const float*)d_in[7];
  const float* Wc  = (const float*)d_in[8];
  const float* Wcb = (const float*)d_in[9];
  const float* Wow = (const float*)d_in[10];
  const float* Wob = (const float*)d_in[11];
  float* out = (float*)d_out;

  char* ws = (char*)d_ws;
  unsigned* cnt = (unsigned*)ws;
  float* zb0 = (float*)(ws + 1024);
  float* zb1 = (float*)(ws + 1024 + HID*4);
  __half* W16 = (__half*)(ws + WOFF);
  size_t wneed = (size_t)WOFF + (size_t)NBLK * GROWS * WPAD * 2;
  bool f16ok = ws_size >= wneed;

  hipMemsetAsync(cnt, 0, 64, stream);
  if (f16ok) {
    prep<<<NBLK*GROWS, 512, 0, stream>>>(Wf, Wi, Wc, W16);
    lstm<true><<<NBLK, TPB, 0, stream>>>(ctx,u,l1w,l1b,Wf,Wfb,Wi,Wib,Wc,Wcb,
                                         Wow,Wob,W16,zb0,zb1,cnt,out);
  } else {
    lstm<false><<<NBLK, TPB, 0, stream>>>(ctx,u,l1w,l1b,Wf,Wfb,Wi,Wib,Wc,Wcb,
                                          Wow,Wob,W16,zb0,zb1,cnt,out);
  }
}